// Round 1
// baseline (7146.969 us; speedup 1.0000x reference)
//
#include <hip/hip_runtime.h>

#define D_MODEL 256
#define T_LEN   96
#define B_SZ    4
#define NROWS   (B_SZ*T_LEN*T_LEN)   // 36864
#define R_PB    32                    // rows per block
#define CPT     16                    // cols per thread (256/16 groups)
#define LDS_STRIDE 264                // 256 + 8 pad: rows land on distinct banks

__device__ __forceinline__ float softplus_f(float x){
    // jax.nn.softplus = max(x,0) + log1p(exp(-|x|))
    return fmaxf(x, 0.0f) + log1pf(__expf(-fabsf(x)));
}

__global__ __launch_bounds__(512)
void ode_rk4_kernel(const float* __restrict__ x, const float* __restrict__ t,
                    const float* __restrict__ W1, const float* __restrict__ b1, const float* __restrict__ u1,
                    const float* __restrict__ W2, const float* __restrict__ b2, const float* __restrict__ u2,
                    float* __restrict__ out)
{
    __shared__ float ytmp[R_PB][LDS_STRIDE];

    const int tid = threadIdx.x;
    const int r   = tid & 31;    // row within block  (wave = 32 rows x 2 col-groups)
    const int c   = tid >> 5;    // col group 0..15
    const int d0  = c * CPT;

    const int n   = blockIdx.x * R_PB + r;        // global pair row: (b, q, j)
    const int b   = n / (T_LEN*T_LEN);
    const int rem = n - b*(T_LEN*T_LEN);
    const int q   = rem / T_LEN;
    const int j   = rem - q*T_LEN;

    const float t0v   = t[b*T_LEN + j];
    const float t1v   = t[b*T_LEN + q];
    const float ratio = t1v - t0v;

    float y[CPT], k1[CPT], k2[CPT], k3[CPT], tmp[CPT];

    {   // y0 = x[b, j, :]
        const float* xr = x + (size_t)(b*T_LEN + j)*D_MODEL + d0;
        #pragma unroll
        for(int i=0;i<CPT;i+=4){
            float4 v = *(const float4*)(xr + i);
            y[i]=v.x; y[i+1]=v.y; y[i+2]=v.z; y[i+3]=v.w;
        }
    }

    // one evaluation of f(s, inv) = (softplus(inv@W1^T + b1 + tt*u1) @ W2^T + b2 + tt*u2) * ratio
    auto eval = [&](const float* inv, float s, float* kout){
        const float tt = t0v + s*ratio;

        __syncthreads();                       // prior matmul2 done reading ytmp
        #pragma unroll
        for(int i=0;i<CPT;i+=4){
            float4 v = make_float4(inv[i],inv[i+1],inv[i+2],inv[i+3]);
            *(float4*)&ytmp[r][d0+i] = v;
        }
        __syncthreads();

        float acc[CPT];
        #pragma unroll
        for(int i=0;i<CPT;i++) acc[i]=0.f;
        for(int k=0;k<D_MODEL;k+=4){
            float4 yv = *(const float4*)&ytmp[r][k];
            #pragma unroll
            for(int i=0;i<CPT;i++){
                float4 w = *(const float4*)(W1 + (size_t)(d0+i)*D_MODEL + k);
                acc[i] = fmaf(yv.x,w.x, fmaf(yv.y,w.y, fmaf(yv.z,w.z, fmaf(yv.w,w.w, acc[i]))));
            }
        }

        __syncthreads();                       // matmul1 done reading ytmp
        #pragma unroll
        for(int i=0;i<CPT;i+=4){
            float4 bv = *(const float4*)(b1 + d0 + i);
            float4 uv = *(const float4*)(u1 + d0 + i);
            float4 h;
            h.x = softplus_f(acc[i+0] + bv.x + tt*uv.x);
            h.y = softplus_f(acc[i+1] + bv.y + tt*uv.y);
            h.z = softplus_f(acc[i+2] + bv.z + tt*uv.z);
            h.w = softplus_f(acc[i+3] + bv.w + tt*uv.w);
            *(float4*)&ytmp[r][d0+i] = h;
        }
        __syncthreads();

        #pragma unroll
        for(int i=0;i<CPT;i++) acc[i]=0.f;
        for(int k=0;k<D_MODEL;k+=4){
            float4 yv = *(const float4*)&ytmp[r][k];
            #pragma unroll
            for(int i=0;i<CPT;i++){
                float4 w = *(const float4*)(W2 + (size_t)(d0+i)*D_MODEL + k);
                acc[i] = fmaf(yv.x,w.x, fmaf(yv.y,w.y, fmaf(yv.z,w.z, fmaf(yv.w,w.w, acc[i]))));
            }
        }
        #pragma unroll
        for(int i=0;i<CPT;i+=4){
            float4 bv = *(const float4*)(b2 + d0 + i);
            float4 uv = *(const float4*)(u2 + d0 + i);
            kout[i+0] = (acc[i+0] + bv.x + tt*uv.x) * ratio;
            kout[i+1] = (acc[i+1] + bv.y + tt*uv.y) * ratio;
            kout[i+2] = (acc[i+2] + bv.z + tt*uv.z) * ratio;
            kout[i+3] = (acc[i+3] + bv.w + tt*uv.w) * ratio;
        }
    };

    const float nodes[3] = {0.1127016653792583f, 0.5f, 0.8872983346207417f};
    const float gwh[3]   = {0.55555f*0.5f, 0.88888f*0.5f, 0.55555f*0.5f};
    const float third    = (1.0f/3.0f);

    float s0 = 0.f;
    #pragma unroll 1
    for(int m=0;m<3;m++){
        const float s1 = nodes[m];
        const float dt = s1 - s0;

        eval(y, s0, k1);                                       // k1
        #pragma unroll
        for(int i=0;i<CPT;i++) tmp[i] = fmaf(dt*third, k1[i], y[i]);
        eval(tmp, s0 + dt*third, k2);                          // k2
        #pragma unroll
        for(int i=0;i<CPT;i++) tmp[i] = fmaf(dt, k2[i] - k1[i]*third, y[i]);
        eval(tmp, s0 + dt*2.0f*third, k3);                     // k3
        #pragma unroll
        for(int i=0;i<CPT;i++) tmp[i] = fmaf(dt, k1[i] - k2[i] + k3[i], y[i]);
        // fold k1..k3 into y before k4 eval (frees them)
        #pragma unroll
        for(int i=0;i<CPT;i++) y[i] = fmaf(dt*0.125f, k1[i] + 3.f*(k2[i]+k3[i]), y[i]);
        eval(tmp, s1, k2);                                     // k4 (reuse k2 slot)
        #pragma unroll
        for(int i=0;i<CPT;i++) y[i] = fmaf(dt*0.125f, k2[i], y[i]);

        // out[b,q,j,m,:] = y * (gauss_w[m]*0.5)
        float* op = out + ((size_t)n*3 + m)*D_MODEL + d0;
        const float g = gwh[m];
        #pragma unroll
        for(int i=0;i<CPT;i+=4){
            float4 v = make_float4(y[i]*g, y[i+1]*g, y[i+2]*g, y[i+3]*g);
            *(float4*)(op + i) = v;
        }
        s0 = s1;
    }
}

extern "C" void kernel_launch(void* const* d_in, const int* in_sizes, int n_in,
                              void* d_out, int out_size, void* d_ws, size_t ws_size,
                              hipStream_t stream)
{
    const float* x  = (const float*)d_in[0];
    const float* t  = (const float*)d_in[1];
    const float* W1 = (const float*)d_in[2];
    const float* b1 = (const float*)d_in[3];
    const float* u1 = (const float*)d_in[4];
    const float* W2 = (const float*)d_in[5];
    const float* b2 = (const float*)d_in[6];
    const float* u2 = (const float*)d_in[7];
    float* out = (float*)d_out;

    dim3 grid(NROWS / R_PB);   // 1152 blocks
    dim3 block(512);
    ode_rk4_kernel<<<grid, block, 0, stream>>>(x, t, W1, b1, u1, W2, b2, u2, out);
}

// Round 2
// 1491.636 us; speedup vs baseline: 4.7914x; 4.7914x over previous
//
#include <hip/hip_runtime.h>

typedef float f32x4 __attribute__((ext_vector_type(4)));
typedef short bf16x8 __attribute__((ext_vector_type(8)));

#define T_LEN 96
#define DM    256
#define NSAMP 64      // ODE rows per block
#define MT 2          // d-tiles per wave (wave owns 32 d)
#define NT 4          // sample-tiles per wave (64 samples)

__device__ __forceinline__ uint bf16h(float x){            // f32 -> bf16 bits, RNE
    uint u = __float_as_uint(x);
    return (u + 0x7fffu + ((u>>16)&1u)) >> 16;
}
__device__ __forceinline__ float bf16f(uint h){ return __uint_as_float(h<<16); }
__device__ __forceinline__ float softplus_f(float x){
    return fmaxf(x,0.f) + log1pf(__expf(-fabsf(x)));
}

// Split W into bf16 hi/lo and pack into MFMA A-fragment order:
// frag (dt,ks): lane l holds W[dt*16 + (l&15)][ks*32 + (l>>4)*8 + i], i=0..7
// => packed[((dt*8+ks)*64 + l)*8 + i]; wave64 load = contiguous 1KB.
__global__ void pack_w_kernel(const float* __restrict__ W1, const float* __restrict__ W2,
                              ushort* __restrict__ ws){
    int idx = blockIdx.x*256 + threadIdx.x;          // 0..65535
    const float* W = blockIdx.y ? W2 : W1;
    ushort* hi = ws + (size_t)blockIdx.y*131072;     // [W1hi|W1lo|W2hi|W2lo], 65536 each
    ushort* lo = hi + 65536;
    float w = W[idx];
    uint h = bf16h(w);
    float l = w - bf16f(h);
    uint l16 = bf16h(l);
    int d = idx >> 8, k = idx & 255;
    int off = ((((d>>4)<<3) + (k>>5))<<9) + (((d&15) | (((k>>3)&3)<<4))<<3) + (k&7);
    hi[off] = (ushort)h;
    lo[off] = (ushort)l16;
}

__global__ __launch_bounds__(512, 2)
void ode_mfma_kernel(const float* __restrict__ x, const float* __restrict__ t,
                     const float* __restrict__ b1, const float* __restrict__ u1,
                     const float* __restrict__ b2, const float* __restrict__ u2,
                     const ushort* __restrict__ wpk, float* __restrict__ out)
{
    // Y stage: [row 0..63][hi 256 | lo 256] bf16, XOR-swizzled in 16B granules
    __shared__ __align__(16) ushort ylds[NSAMP*512];

    const int tid  = threadIdx.x;
    const int wv   = tid >> 6;      // wave 0..7 -> d in [32w, 32w+32)
    const int lane = tid & 63;
    const int l15  = lane & 15;
    const int l4   = lane >> 4;
    const int base = blockIdx.x * NSAMP;

    int   bj[NT]; int nglob[NT];
    float t0v[NT], rat[NT];
#pragma unroll
    for(int nt=0; nt<NT; nt++){
        int n = base + nt*16 + l15;
        nglob[nt] = n;
        int b = n / (T_LEN*T_LEN);
        int r = n - b*(T_LEN*T_LEN);
        int q = r / T_LEN;
        int j = r - q*T_LEN;
        bj[nt] = b*T_LEN + j;
        float ta = t[b*T_LEN + j], tb = t[b*T_LEN + q];
        t0v[nt] = ta; rat[nt] = tb - ta;
    }

    float y[MT][NT][4], k1[MT][NT][4], k2[MT][NT][4];
    f32x4 acc[MT][NT];

#pragma unroll
    for(int mt=0; mt<MT; mt++){
        const int db = 32*wv + mt*16 + l4*4;
#pragma unroll
        for(int nt=0; nt<NT; nt++){
            f32x4 v = *(const f32x4*)(x + (size_t)bj[nt]*DM + db);
#pragma unroll
            for(int r2=0;r2<4;r2++) y[mt][nt][r2] = v[r2];
        }
    }

    // write 4 consecutive-d values (one D-fragment reg group) as hi/lo bf16 into ylds
    auto put = [&](int mt, int nt, float v0, float v1, float v2, float v3){
        uint h0=bf16h(v0), h1=bf16h(v1), h2=bf16h(v2), h3=bf16h(v3);
        uint hp0 = h0 | (h1<<16), hp1 = h2 | (h3<<16);
        uint lp0 = bf16h(v0 - bf16f(h0)) | (bf16h(v1 - bf16f(h1))<<16);
        uint lp1 = bf16h(v2 - bf16f(h2)) | (bf16h(v3 - bf16f(h3))<<16);
        int row = nt*16 + l15;
        int g = (4*wv + 2*mt + (l4>>1)) ^ ((row&7)<<2);
        int idx = row*512 + g*8 + (l4&1)*4;
        *(uint2*)&ylds[idx]       = make_uint2(hp0, hp1);   // hi half
        *(uint2*)&ylds[idx + 256] = make_uint2(lp0, lp1);   // lo half
    };

    // acc[mt][nt] = (W-slice) x Y^T over K=256, 3-product bf16 split
    auto matmul = [&](const ushort* Whi){
        const ushort* Wlo = Whi + 65536;
#pragma unroll
        for(int mt=0; mt<MT; mt++)
#pragma unroll
            for(int nt=0; nt<NT; nt++)
                acc[mt][nt] = (f32x4){0.f,0.f,0.f,0.f};
#pragma unroll 2
        for(int ks=0; ks<8; ks++){
            bf16x8 ah[MT], al[MT];
#pragma unroll
            for(int mt=0; mt<MT; mt++){
                const int off = ((((2*wv+mt)<<3)+ks)<<9) + (lane<<3);
                ah[mt] = *(const bf16x8*)(Whi + off);
                al[mt] = *(const bf16x8*)(Wlo + off);
            }
            bf16x8 bh[NT], bl[NT];
#pragma unroll
            for(int nt=0; nt<NT; nt++){
                const int row = nt*16 + l15;
                const int gx  = ((ks ^ (row&7))<<2) | l4;
                const ushort* bp = &ylds[row*512 + gx*8];
                bh[nt] = *(const bf16x8*)bp;
                bl[nt] = *(const bf16x8*)(bp + 256);
            }
#pragma unroll
            for(int mt=0; mt<MT; mt++)
#pragma unroll
                for(int nt=0; nt<NT; nt++){
                    acc[mt][nt] = __builtin_amdgcn_mfma_f32_16x16x32_bf16(ah[mt], bh[nt], acc[mt][nt], 0,0,0);
                    acc[mt][nt] = __builtin_amdgcn_mfma_f32_16x16x32_bf16(ah[mt], bl[nt], acc[mt][nt], 0,0,0);
                    acc[mt][nt] = __builtin_amdgcn_mfma_f32_16x16x32_bf16(al[mt], bh[nt], acc[mt][nt], 0,0,0);
                }
        }
    };

    // input already staged by caller; leaves layer-2 raw acc for caller to finish
    auto eval = [&](const float* ttv){
        __syncthreads();                 // stage writes visible
        matmul(wpk);                     // layer 1
        __syncthreads();                 // all reads of input stage done
#pragma unroll
        for(int mt=0; mt<MT; mt++){
            const int db = 32*wv + mt*16 + l4*4;
            f32x4 bv = *(const f32x4*)(b1 + db);
            f32x4 uv = *(const f32x4*)(u1 + db);
#pragma unroll
            for(int nt=0; nt<NT; nt++){
                float v[4];
#pragma unroll
                for(int r2=0;r2<4;r2++)
                    v[r2] = softplus_f(acc[mt][nt][r2] + bv[r2] + ttv[nt]*uv[r2]);
                put(mt, nt, v[0], v[1], v[2], v[3]);
            }
        }
        __syncthreads();
        matmul(wpk + 131072);            // layer 2
    };

    float s0 = 0.f;
#pragma unroll 1
    for(int step=0; step<3; step++){
        const float s1 = (step==0) ? 0.1127016653792583f : ((step==1) ? 0.5f : 0.8872983346207417f);
        const float gw = ((step==1) ? 0.88888f : 0.55555f) * 0.5f;
        const float dt = s1 - s0;
        const float c3 = dt * (1.f/3.f);
        const float dt8 = dt * 0.125f;
        float tt[NT];

        // ---- eval 1: f(s0, y) -> k1
        __syncthreads();
#pragma unroll
        for(int mt=0; mt<MT; mt++)
#pragma unroll
            for(int nt=0; nt<NT; nt++)
                put(mt, nt, y[mt][nt][0], y[mt][nt][1], y[mt][nt][2], y[mt][nt][3]);
#pragma unroll
        for(int nt=0; nt<NT; nt++) tt[nt] = t0v[nt] + s0*rat[nt];
        eval(tt);

        // ---- k1 extract; stage y + (dt/3)k1
        __syncthreads();
#pragma unroll
        for(int mt=0; mt<MT; mt++){
            const int db = 32*wv + mt*16 + l4*4;
            f32x4 bv = *(const f32x4*)(b2 + db);
            f32x4 uv = *(const f32x4*)(u2 + db);
#pragma unroll
            for(int nt=0; nt<NT; nt++){
                float v[4];
#pragma unroll
                for(int r2=0;r2<4;r2++){
                    float kk = (acc[mt][nt][r2] + bv[r2] + tt[nt]*uv[r2]) * rat[nt];
                    k1[mt][nt][r2] = kk;
                    v[r2] = fmaf(c3, kk, y[mt][nt][r2]);
                }
                put(mt, nt, v[0], v[1], v[2], v[3]);
            }
        }
#pragma unroll
        for(int nt=0; nt<NT; nt++) tt[nt] = t0v[nt] + (s0+c3)*rat[nt];
        eval(tt);

        // ---- k2 extract; stage y + dt*k2 - (dt/3)k1
        __syncthreads();
#pragma unroll
        for(int mt=0; mt<MT; mt++){
            const int db = 32*wv + mt*16 + l4*4;
            f32x4 bv = *(const f32x4*)(b2 + db);
            f32x4 uv = *(const f32x4*)(u2 + db);
#pragma unroll
            for(int nt=0; nt<NT; nt++){
                float v[4];
#pragma unroll
                for(int r2=0;r2<4;r2++){
                    float kk = (acc[mt][nt][r2] + bv[r2] + tt[nt]*uv[r2]) * rat[nt];
                    k2[mt][nt][r2] = kk;
                    v[r2] = y[mt][nt][r2] + dt*kk - c3*k1[mt][nt][r2];
                }
                put(mt, nt, v[0], v[1], v[2], v[3]);
            }
        }
#pragma unroll
        for(int nt=0; nt<NT; nt++) tt[nt] = t0v[nt] + (s0+2.f*c3)*rat[nt];
        eval(tt);

        // ---- k3 extract (folded): stage y + dt*(k1-k2+k3); y += dt8*(k1+3(k2+k3))
        __syncthreads();
#pragma unroll
        for(int mt=0; mt<MT; mt++){
            const int db = 32*wv + mt*16 + l4*4;
            f32x4 bv = *(const f32x4*)(b2 + db);
            f32x4 uv = *(const f32x4*)(u2 + db);
#pragma unroll
            for(int nt=0; nt<NT; nt++){
                float v[4];
#pragma unroll
                for(int r2=0;r2<4;r2++){
                    float k3v = (acc[mt][nt][r2] + bv[r2] + tt[nt]*uv[r2]) * rat[nt];
                    float yo = y[mt][nt][r2];
                    v[r2] = yo + dt*(k1[mt][nt][r2] - k2[mt][nt][r2] + k3v);
                    y[mt][nt][r2] = yo + dt8*(k1[mt][nt][r2] + 3.f*(k2[mt][nt][r2] + k3v));
                }
                put(mt, nt, v[0], v[1], v[2], v[3]);
            }
        }
#pragma unroll
        for(int nt=0; nt<NT; nt++) tt[nt] = t0v[nt] + s1*rat[nt];
        eval(tt);

        // ---- k4 fold + output write
#pragma unroll
        for(int mt=0; mt<MT; mt++){
            const int db = 32*wv + mt*16 + l4*4;
            f32x4 bv = *(const f32x4*)(b2 + db);
            f32x4 uv = *(const f32x4*)(u2 + db);
#pragma unroll
            for(int nt=0; nt<NT; nt++){
                f32x4 ov;
#pragma unroll
                for(int r2=0;r2<4;r2++){
                    float k4v = (acc[mt][nt][r2] + bv[r2] + tt[nt]*uv[r2]) * rat[nt];
                    float yn = fmaf(dt8, k4v, y[mt][nt][r2]);
                    y[mt][nt][r2] = yn;
                    ov[r2] = yn * gw;
                }
                *(f32x4*)(out + ((size_t)nglob[nt]*3 + step)*DM + db) = ov;
            }
        }
        s0 = s1;
    }
}

extern "C" void kernel_launch(void* const* d_in, const int* in_sizes, int n_in,
                              void* d_out, int out_size, void* d_ws, size_t ws_size,
                              hipStream_t stream)
{
    const float* x  = (const float*)d_in[0];
    const float* t  = (const float*)d_in[1];
    const float* W1 = (const float*)d_in[2];
    const float* b1 = (const float*)d_in[3];
    const float* u1 = (const float*)d_in[4];
    const float* W2 = (const float*)d_in[5];
    const float* b2 = (const float*)d_in[6];
    const float* u2 = (const float*)d_in[7];
    ushort* wpk = (ushort*)d_ws;     // 512 KB: W1hi|W1lo|W2hi|W2lo packed fragments

    pack_w_kernel<<<dim3(256,2), 256, 0, stream>>>(W1, W2, wpk);
    ode_mfma_kernel<<<dim3((4*T_LEN*T_LEN)/NSAMP), 512, 0, stream>>>(
        x, t, b1, u1, b2, u2, wpk, (float*)d_out);
}